// Round 5
// baseline (1421.012 us; speedup 1.0000x reference)
//
#include <hip/hip_runtime.h>
#include <hip/hip_fp16.h>
#include <math.h>

// GCN: h1 = relu(norm_agg(x@W1) + b1); h2 = relu(norm_agg(h1@W2) + b2);
// out = sigmoid(h2@fc_w + fc_b)
// norm_agg(z)[d] = dinv[d]*( sum_{s->d} dinv[s]*z[s] + dinv[d]*z[d] )
//
// Round 5: k_agg is L2-miss-rate bound (~1.2 fills/cyc/XCD both R3+R4 at
// identical 684us). Fix locality, not bytes: per-bucket counting sort of edges
// by src-slab (32 slabs x 16K nodes). Co-resident agg blocks walk slabs in
// lockstep -> per-XCD hot set ~1MB << 4MB L2 -> gathers become L2 hits.

#define SHIFT 9
#define BSZ 512              // nodes per bucket (1<<SHIFT)
#define EB 2048              // edge-chunk blocks for hist/part
#define SRCMASK 0x7FFFFu     // 19 bits: N <= 524288
#define NSLAB 32
#define SLABSH 14            // slab = src >> 14 (19-bit src -> 32 slabs)

static inline int idiv_up(long a, long b) { return (int)((a + b - 1) / b); }

// ---------------- partition pass ----------------
__global__ void k_hist(const int* __restrict__ dst, long E, long chunk,
                       unsigned* __restrict__ C, int NBUCK) {
    __shared__ unsigned cnt[1024];
    for (int t = threadIdx.x; t < 1024; t += 256) cnt[t] = 0u;
    __syncthreads();
    long e0 = (long)blockIdx.x * chunk;
    long e1 = e0 + chunk; if (e1 > E) e1 = E;
    for (long k = e0 + threadIdx.x; k < e1; k += 256)
        atomicAdd(&cnt[(unsigned)dst[k] >> SHIFT], 1u);
    __syncthreads();
    for (int bk = threadIdx.x; bk < NBUCK; bk += 256)
        C[(size_t)bk * EB + blockIdx.x] = cnt[bk];
}

__global__ void k_bsum(const unsigned* __restrict__ in, long L, unsigned* __restrict__ bsum) {
    __shared__ unsigned s[256];
    long base = (long)blockIdx.x * 1024 + threadIdx.x * 4;
    unsigned t = 0;
#pragma unroll
    for (int j = 0; j < 4; ++j) { long idx = base + j; if (idx < L) t += in[idx]; }
    s[threadIdx.x] = t;
    __syncthreads();
    for (int o = 128; o > 0; o >>= 1) {
        if (threadIdx.x < (unsigned)o) s[threadIdx.x] += s[threadIdx.x + o];
        __syncthreads();
    }
    if (threadIdx.x == 0) bsum[blockIdx.x] = s[0];
}

__global__ void k_scan_boff(unsigned* bsum, int NB) {
    __shared__ unsigned s[512];
    unsigned carry = 0;
    for (int base = 0; base < NB; base += 512) {
        int idx = base + threadIdx.x;
        unsigned v = (idx < NB) ? bsum[idx] : 0u;
        s[threadIdx.x] = v;
        __syncthreads();
        for (int o = 1; o < 512; o <<= 1) {
            unsigned a = (threadIdx.x >= (unsigned)o) ? s[threadIdx.x - o] : 0u;
            __syncthreads();
            s[threadIdx.x] += a;
            __syncthreads();
        }
        if (idx < NB) bsum[idx] = carry + s[threadIdx.x] - v;  // exclusive
        unsigned tot = s[511];
        __syncthreads();
        carry += tot;
    }
}

__global__ void k_scan_final(const unsigned* __restrict__ in, long L,
                             const unsigned* __restrict__ boff, unsigned* __restrict__ out) {
    __shared__ unsigned s[256];
    long base = (long)blockIdx.x * 1024 + threadIdx.x * 4;
    unsigned v[4]; unsigned t = 0;
#pragma unroll
    for (int j = 0; j < 4; ++j) { long idx = base + j; v[j] = (idx < L) ? in[idx] : 0u; t += v[j]; }
    s[threadIdx.x] = t;
    __syncthreads();
    for (int o = 1; o < 256; o <<= 1) {
        unsigned a = (threadIdx.x >= (unsigned)o) ? s[threadIdx.x - o] : 0u;
        __syncthreads();
        s[threadIdx.x] += a;
        __syncthreads();
    }
    unsigned run = s[threadIdx.x] - t + boff[blockIdx.x];
#pragma unroll
    for (int j = 0; j < 4; ++j) {
        long idx = base + j;
        if (idx < L) { out[idx] = run; run += v[j]; }
    }
}

__global__ void k_part(const int* __restrict__ src, const int* __restrict__ dst, long E,
                       long chunk, const unsigned* __restrict__ Coff,
                       unsigned* __restrict__ P, int NBUCK) {
    __shared__ unsigned cur[1024];
    for (int bk = threadIdx.x; bk < NBUCK; bk += 256)
        cur[bk] = Coff[(size_t)bk * EB + blockIdx.x];
    __syncthreads();
    long e0 = (long)blockIdx.x * chunk;
    long e1 = e0 + chunk; if (e1 > E) e1 = E;
    for (long k = e0 + threadIdx.x; k < e1; k += 256) {
        unsigned s = (unsigned)src[k], d = (unsigned)dst[k];
        unsigned bk = d >> SHIFT;
        unsigned pos = atomicAdd(&cur[bk], 1u);  // LDS atomic
        P[pos] = s | ((d & (BSZ - 1u)) << 19);
    }
}

// per-bucket counting sort by src-slab: Pin -> Pout (same bucket ranges)
__global__ __launch_bounds__(512) void k_sortslab(const unsigned* __restrict__ Pin,
                                                  const unsigned* __restrict__ Coff, long E,
                                                  int NBUCK, unsigned* __restrict__ Pout) {
    __shared__ unsigned cnt[NSLAB];
    __shared__ unsigned base_s[NSLAB];
    int b = blockIdx.x;
    long bs = Coff[(size_t)b * EB];
    long be = (b + 1 < NBUCK) ? (long)Coff[(size_t)(b + 1) * EB] : E;
    if (threadIdx.x < NSLAB) cnt[threadIdx.x] = 0u;
    __syncthreads();
    for (long k = bs + threadIdx.x; k < be; k += 512)
        atomicAdd(&cnt[(Pin[k] & SRCMASK) >> SLABSH], 1u);
    __syncthreads();
    if (threadIdx.x == 0) {  // 32-entry serial exclusive scan
        unsigned run = 0;
#pragma unroll
        for (int i = 0; i < NSLAB; ++i) { base_s[i] = run; run += cnt[i]; }
    }
    __syncthreads();
    if (threadIdx.x < NSLAB) cnt[threadIdx.x] = base_s[threadIdx.x];  // -> cursors
    __syncthreads();
    for (long k = bs + threadIdx.x; k < be; k += 512) {
        unsigned v = Pin[k];
        unsigned pos = atomicAdd(&cnt[(v & SRCMASK) >> SLABSH], 1u);
        Pout[bs + pos] = v;
    }
}

__global__ void k_bdeg(const unsigned* __restrict__ P, const unsigned* __restrict__ Coff,
                       long E, int NBUCK, float* __restrict__ dinv, int N) {
    __shared__ unsigned cnt[BSZ];
    for (int t = threadIdx.x; t < BSZ; t += 256) cnt[t] = 0u;
    int b = blockIdx.x;
    long bs = Coff[(size_t)b * EB];
    long be = (b + 1 < NBUCK) ? (long)Coff[(size_t)(b + 1) * EB] : E;
    __syncthreads();
    for (long k = bs + threadIdx.x; k < be; k += 256)
        atomicAdd(&cnt[P[k] >> 19], 1u);
    __syncthreads();
    int base = b << SHIFT;
    for (int t = threadIdx.x; t < BSZ; t += 256) {
        int node = base + t;
        if (node < N) dinv[node] = rsqrtf((float)(cnt[t] + 1u));
    }
}

// ---------------- aggregation (fp16 y, unrolled, 512 threads) ----------------
template <int C>
__device__ inline void loadrow(const __half* __restrict__ y, unsigned v, uint4* r) {
    unsigned s = v & SRCMASK;
    const uint4* yp = (const uint4*)(y + (size_t)s * C);
#pragma unroll
    for (int q = 0; q < C / 8; ++q) r[q] = yp[q];
}

template <int C>
__device__ inline void scatrow(float* __restrict__ sacc, unsigned v, const uint4* r) {
    unsigned dl = v >> 19;
#pragma unroll
    for (int q = 0; q < C / 8; ++q) {
        const __half2* hp = (const __half2*)&r[q];
#pragma unroll
        for (int j = 0; j < 4; ++j) {
            float2 f = __half22float2(hp[j]);
            atomicAdd(&sacc[(q * 8 + 2 * j + 0) * BSZ + dl], f.x);  // ds_add_f32
            atomicAdd(&sacc[(q * 8 + 2 * j + 1) * BSZ + dl], f.y);
        }
    }
}

template <int C>
__global__ __launch_bounds__(512) void k_agg(const unsigned* __restrict__ P,
                                             const unsigned* __restrict__ Coff, long E, int NBUCK,
                                             const __half* __restrict__ y,
                                             float* __restrict__ accG, int N) {
    __shared__ float sacc[C * BSZ];
    for (int t = threadIdx.x; t < C * BSZ; t += 512) sacc[t] = 0.f;
    int b = blockIdx.x;
    long bs = Coff[(size_t)b * EB];
    long be = (b + 1 < NBUCK) ? (long)Coff[(size_t)(b + 1) * EB] : E;
    __syncthreads();
    const long T = 512;
    long k = bs + threadIdx.x;
    for (; k + 3 * T < be; k += 4 * T) {  // 4 independent gathers in flight
        unsigned v0 = P[k], v1 = P[k + T], v2 = P[k + 2 * T], v3 = P[k + 3 * T];
        uint4 r0[C / 8], r1[C / 8], r2[C / 8], r3[C / 8];
        loadrow<C>(y, v0, r0);
        loadrow<C>(y, v1, r1);
        loadrow<C>(y, v2, r2);
        loadrow<C>(y, v3, r3);
        scatrow<C>(sacc, v0, r0);
        scatrow<C>(sacc, v1, r1);
        scatrow<C>(sacc, v2, r2);
        scatrow<C>(sacc, v3, r3);
    }
    for (; k < be; k += T) {
        unsigned v = P[k];
        uint4 r[C / 8];
        loadrow<C>(y, v, r);
        scatrow<C>(sacc, v, r);
    }
    __syncthreads();
    int t = threadIdx.x;
    int node = (b << SHIFT) + t;
    if (node < N) {
        const __half* yn = y + (size_t)node * C;
        float4* op = (float4*)(accG + (size_t)node * C);
#pragma unroll
        for (int q = 0; q < C / 4; ++q) {
            float4 o;
            o.x = sacc[(4 * q + 0) * BSZ + t] + __half2float(yn[4 * q + 0]);
            o.y = sacc[(4 * q + 1) * BSZ + t] + __half2float(yn[4 * q + 1]);
            o.z = sacc[(4 * q + 2) * BSZ + t] + __half2float(yn[4 * q + 2]);
            o.w = sacc[(4 * q + 3) * BSZ + t] + __half2float(yn[4 * q + 3]);
            op[q] = o;
        }
    }
}

// ---------------- node kernels ----------------
__device__ inline uint4 pack8h(const float* o) {
    union { __half2 h2[4]; uint4 u; } z;
    z.h2[0] = __floats2half2_rn(o[0], o[1]);
    z.h2[1] = __floats2half2_rn(o[2], o[3]);
    z.h2[2] = __floats2half2_rn(o[4], o[5]);
    z.h2[3] = __floats2half2_rn(o[6], o[7]);
    return z.u;
}

__global__ void k_node1(const float* __restrict__ x, const float* __restrict__ W1,
                        const float* __restrict__ dinv, __half* __restrict__ y1h, int N) {
    __shared__ float sW[192];  // W1 [12][16]
    if (threadIdx.x < 192) sW[threadIdx.x] = W1[threadIdx.x];
    __syncthreads();
    int i = blockIdx.x * blockDim.x + threadIdx.x;
    if (i >= N) return;
    const float4* xp = (const float4*)(x + (size_t)i * 12);
    float4 a = xp[0], b = xp[1], c = xp[2];
    float xi[12] = {a.x, a.y, a.z, a.w, b.x, b.y, b.z, b.w, c.x, c.y, c.z, c.w};
    float di = dinv[i];
    float o[16];
#pragma unroll
    for (int cc = 0; cc < 16; ++cc) {
        float s = 0.f;
#pragma unroll
        for (int r = 0; r < 12; ++r) s = fmaf(xi[r], sW[r * 16 + cc], s);
        o[cc] = s * di;
    }
    uint4* yp = (uint4*)(y1h + (size_t)i * 16);
    yp[0] = pack8h(o);
    yp[1] = pack8h(o + 8);
}

__global__ void k_node2(const float* __restrict__ acc1, const float* __restrict__ W2,
                        const float* __restrict__ b1, const float* __restrict__ dinv,
                        __half* __restrict__ y2h, int N) {
    __shared__ float sW[128];  // W2 [16][8]
    __shared__ float sb[16];
    if (threadIdx.x < 128) sW[threadIdx.x] = W2[threadIdx.x];
    if (threadIdx.x < 16) sb[threadIdx.x] = b1[threadIdx.x];
    __syncthreads();
    int i = blockIdx.x * blockDim.x + threadIdx.x;
    if (i >= N) return;
    float di = dinv[i];
    const float4* ap = (const float4*)(acc1 + (size_t)i * 16);
    float h[16];
#pragma unroll
    for (int q = 0; q < 4; ++q) {
        float4 v = ap[q];
        h[4 * q + 0] = fmaxf(fmaf(v.x, di, sb[4 * q + 0]), 0.f);
        h[4 * q + 1] = fmaxf(fmaf(v.y, di, sb[4 * q + 1]), 0.f);
        h[4 * q + 2] = fmaxf(fmaf(v.z, di, sb[4 * q + 2]), 0.f);
        h[4 * q + 3] = fmaxf(fmaf(v.w, di, sb[4 * q + 3]), 0.f);
    }
    float o[8];
#pragma unroll
    for (int k = 0; k < 8; ++k) {
        float s = 0.f;
#pragma unroll
        for (int c = 0; c < 16; ++c) s = fmaf(h[c], sW[c * 8 + k], s);
        o[k] = s * di;
    }
    *(uint4*)(y2h + (size_t)i * 8) = pack8h(o);
}

__global__ void k_node3(const float* __restrict__ acc2, const float* __restrict__ b2,
                        const float* __restrict__ fcw, const float* __restrict__ fcb,
                        const float* __restrict__ dinv, float* __restrict__ out, int N) {
    __shared__ float sb[8], sw[8], sfb[1];
    if (threadIdx.x < 8) {
        sb[threadIdx.x] = b2[threadIdx.x];
        sw[threadIdx.x] = fcw[threadIdx.x];
    }
    if (threadIdx.x == 0) sfb[0] = fcb[0];
    __syncthreads();
    int i = blockIdx.x * blockDim.x + threadIdx.x;
    if (i >= N) return;
    float di = dinv[i];
    const float4* ap = (const float4*)(acc2 + (size_t)i * 8);
    float s = sfb[0];
#pragma unroll
    for (int q = 0; q < 2; ++q) {
        float4 v = ap[q];
        s = fmaf(fmaxf(fmaf(v.x, di, sb[4 * q + 0]), 0.f), sw[4 * q + 0], s);
        s = fmaf(fmaxf(fmaf(v.y, di, sb[4 * q + 1]), 0.f), sw[4 * q + 1], s);
        s = fmaf(fmaxf(fmaf(v.z, di, sb[4 * q + 2]), 0.f), sw[4 * q + 2], s);
        s = fmaf(fmaxf(fmaf(v.w, di, sb[4 * q + 3]), 0.f), sw[4 * q + 3], s);
    }
    out[i] = 1.f / (1.f + expf(-s));
}

// ---------------- fallback path (f32, global atomics) ----------------
__global__ void k_deg(const int* __restrict__ dst, long E, unsigned* __restrict__ deg) {
    long i = (long)blockIdx.x * blockDim.x + threadIdx.x;
    long stride = (long)gridDim.x * blockDim.x;
    for (long e = i; e < E; e += stride)
        atomicAdd(&deg[dst[e]], 1u);
}

__global__ void k_dinv(const unsigned* __restrict__ deg, float* __restrict__ dinv, int N) {
    int i = blockIdx.x * blockDim.x + threadIdx.x;
    if (i < N) dinv[i] = rsqrtf((float)(deg[i] + 1u));
}

__global__ void k_node1f(const float* __restrict__ x, const float* __restrict__ W1,
                         const float* __restrict__ dinv, float* __restrict__ y1,
                         float* __restrict__ acc1, int N) {
    __shared__ float sW[192];
    if (threadIdx.x < 192) sW[threadIdx.x] = W1[threadIdx.x];
    __syncthreads();
    int i = blockIdx.x * blockDim.x + threadIdx.x;
    if (i >= N) return;
    const float4* xp = (const float4*)(x + (size_t)i * 12);
    float4 a = xp[0], b = xp[1], c = xp[2];
    float xi[12] = {a.x, a.y, a.z, a.w, b.x, b.y, b.z, b.w, c.x, c.y, c.z, c.w};
    float di = dinv[i];
    float o[16];
#pragma unroll
    for (int cc = 0; cc < 16; ++cc) {
        float s = 0.f;
#pragma unroll
        for (int r = 0; r < 12; ++r) s = fmaf(xi[r], sW[r * 16 + cc], s);
        o[cc] = s * di;
    }
    float4* yp = (float4*)(y1 + (size_t)i * 16);
    float4* ap = (float4*)(acc1 + (size_t)i * 16);
#pragma unroll
    for (int q = 0; q < 4; ++q) {
        float4 v = make_float4(o[4 * q], o[4 * q + 1], o[4 * q + 2], o[4 * q + 3]);
        yp[q] = v; ap[q] = v;
    }
}

__global__ void k_node2f(const float* __restrict__ acc1, const float* __restrict__ W2,
                         const float* __restrict__ b1, const float* __restrict__ dinv,
                         float* __restrict__ y2, float* __restrict__ acc2, int N) {
    __shared__ float sW[128];
    __shared__ float sb[16];
    if (threadIdx.x < 128) sW[threadIdx.x] = W2[threadIdx.x];
    if (threadIdx.x < 16) sb[threadIdx.x] = b1[threadIdx.x];
    __syncthreads();
    int i = blockIdx.x * blockDim.x + threadIdx.x;
    if (i >= N) return;
    float di = dinv[i];
    const float4* ap = (const float4*)(acc1 + (size_t)i * 16);
    float h[16];
#pragma unroll
    for (int q = 0; q < 4; ++q) {
        float4 v = ap[q];
        h[4 * q + 0] = fmaxf(fmaf(v.x, di, sb[4 * q + 0]), 0.f);
        h[4 * q + 1] = fmaxf(fmaf(v.y, di, sb[4 * q + 1]), 0.f);
        h[4 * q + 2] = fmaxf(fmaf(v.z, di, sb[4 * q + 2]), 0.f);
        h[4 * q + 3] = fmaxf(fmaf(v.w, di, sb[4 * q + 3]), 0.f);
    }
    float o[8];
#pragma unroll
    for (int k = 0; k < 8; ++k) {
        float s = 0.f;
#pragma unroll
        for (int c = 0; c < 16; ++c) s = fmaf(h[c], sW[c * 8 + k], s);
        o[k] = s * di;
    }
    float4* yp = (float4*)(y2 + (size_t)i * 8);
    float4* a2 = (float4*)(acc2 + (size_t)i * 8);
#pragma unroll
    for (int q = 0; q < 2; ++q) {
        float4 v = make_float4(o[4 * q], o[4 * q + 1], o[4 * q + 2], o[4 * q + 3]);
        yp[q] = v; a2[q] = v;
    }
}

template <int C>
__global__ void k_edge(const int* __restrict__ src, const int* __restrict__ dst, long E,
                       const float* __restrict__ y, float* __restrict__ acc) {
    long i = (long)blockIdx.x * blockDim.x + threadIdx.x;
    long stride = (long)gridDim.x * blockDim.x;
    for (long e = i; e < E; e += stride) {
        int s = src[e], d = dst[e];
        const float4* ys = (const float4*)(y + (size_t)s * C);
        float* ad = acc + (size_t)d * C;
#pragma unroll
        for (int q = 0; q < C / 4; ++q) {
            float4 v = ys[q];
            unsafeAtomicAdd(ad + 4 * q + 0, v.x);
            unsafeAtomicAdd(ad + 4 * q + 1, v.y);
            unsafeAtomicAdd(ad + 4 * q + 2, v.z);
            unsafeAtomicAdd(ad + 4 * q + 3, v.w);
        }
    }
}

extern "C" void kernel_launch(void* const* d_in, const int* in_sizes, int n_in,
                              void* d_out, int out_size, void* d_ws, size_t ws_size,
                              hipStream_t stream) {
    const float* x   = (const float*)d_in[0];
    const int*   ei  = (const int*)d_in[1];
    const float* W1  = (const float*)d_in[2];
    const float* b1  = (const float*)d_in[3];
    const float* W2  = (const float*)d_in[4];
    const float* b2  = (const float*)d_in[5];
    const float* fcw = (const float*)d_in[6];
    const float* fcb = (const float*)d_in[7];
    float* out = (float*)d_out;

    const long N = in_sizes[0] / 12;
    const long E = in_sizes[1] / 2;
    const int* src = ei;
    const int* dst = ei + E;

    const int NBUCK = idiv_up(N, BSZ);
    const long L = (long)NBUCK * EB;
    const int NB2 = idiv_up(L, 1024);
    const long chunk = (E + EB - 1) / EB;

    char* ws = (char*)d_ws;
    size_t off = 0;
    auto alloc = [&](size_t bytes) {
        void* p = ws + off;
        off += (bytes + 255) & ~(size_t)255;
        return p;
    };
    unsigned* C    = (unsigned*)alloc((size_t)L * 4);      // scanned in-place -> Coff
    unsigned* bsum = (unsigned*)alloc((size_t)NB2 * 4);
    unsigned* P    = (unsigned*)alloc((size_t)E * 4);      // packed (src | dlow<<19)
    unsigned* P2   = (unsigned*)alloc((size_t)E * 4);      // slab-sorted
    float*    dinv = (float*)alloc((size_t)N * 4);
    __half*   y1h  = (__half*)alloc((size_t)N * 16 * 2);   // fp16 rows
    float*    acc1 = (float*)alloc((size_t)N * 16 * 4);
    __half*   y2h  = y1h;                                  // y1h dead after agg16
    float*    acc2 = acc1;                                 // acc1 dead after node2
    const bool use_new = (N <= 524288) && (off <= ws_size);

    const int B = 256;
    const int NG = idiv_up(N, B);

    if (use_new) {
        k_hist<<<EB, B, 0, stream>>>(dst, E, chunk, C, NBUCK);
        k_bsum<<<NB2, B, 0, stream>>>(C, L, bsum);
        k_scan_boff<<<1, 512, 0, stream>>>(bsum, NB2);
        k_scan_final<<<NB2, B, 0, stream>>>(C, L, bsum, C);
        k_part<<<EB, B, 0, stream>>>(src, dst, E, chunk, C, P, NBUCK);
        k_sortslab<<<NBUCK, 512, 0, stream>>>(P, C, E, NBUCK, P2);
        k_bdeg<<<NBUCK, B, 0, stream>>>(P2, C, E, NBUCK, dinv, (int)N);
        k_node1<<<NG, B, 0, stream>>>(x, W1, dinv, y1h, (int)N);
        k_agg<16><<<NBUCK, 512, 0, stream>>>(P2, C, E, NBUCK, y1h, acc1, (int)N);
        k_node2<<<NG, B, 0, stream>>>(acc1, W2, b1, dinv, y2h, (int)N);
        k_agg<8><<<NBUCK, 512, 0, stream>>>(P2, C, E, NBUCK, y2h, acc2, (int)N);
        k_node3<<<NG, B, 0, stream>>>(acc2, b2, fcw, fcb, dinv, out, (int)N);
    } else {
        // fallback: round-1 atomic path (f32)
        size_t off2 = 0;
        auto alloc2 = [&](size_t bytes) {
            void* p = ws + off2;
            off2 += (bytes + 255) & ~(size_t)255;
            return p;
        };
        unsigned* degF  = (unsigned*)alloc2((size_t)N * 4);
        float*    dinvF = (float*)alloc2((size_t)N * 4);
        float*    y1F   = (float*)alloc2((size_t)N * 16 * 4);
        float*    acc1F = (float*)alloc2((size_t)N * 16 * 4);
        float*    y2F   = y1F;
        float*    acc2F = y1F + N * 8;
        const int EG = 2048;
        hipMemsetAsync(degF, 0, (size_t)N * 4, stream);
        k_deg<<<EG, B, 0, stream>>>(dst, E, degF);
        k_dinv<<<NG, B, 0, stream>>>(degF, dinvF, (int)N);
        k_node1f<<<NG, B, 0, stream>>>(x, W1, dinvF, y1F, acc1F, (int)N);
        k_edge<16><<<EG, B, 0, stream>>>(src, dst, E, y1F, acc1F);
        k_node2f<<<NG, B, 0, stream>>>(acc1F, W2, b1, dinvF, y2F, acc2F, (int)N);
        k_edge<8><<<EG, B, 0, stream>>>(src, dst, E, y2F, acc2F);
        k_node3<<<NG, B, 0, stream>>>(acc2F, b2, fcw, fcb, dinvF, out, (int)N);
    }
}

// Round 6
// 1394.681 us; speedup vs baseline: 1.0189x; 1.0189x over previous
//
#include <hip/hip_runtime.h>
#include <hip/hip_fp16.h>
#include <math.h>

// GCN: h1 = relu(norm_agg(x@W1) + b1); h2 = relu(norm_agg(h1@W2) + b2);
// out = sigmoid(h2@fc_w + fc_b)
// norm_agg(z)[d] = dinv[d]*( sum_{s->d} dinv[s]*z[s] + dinv[d]*z[d] )
//
// Round 6: R3/R4/R5 invariant: ~8M divergent VMEM requests pin at ~11.7G/s
// regardless of occupancy/bytes/L2-hits. Eliminate random access entirely:
// two-phase expand/compress SpMM. Src-sort edges; k_expand stages each
// src-bucket's y rows in LDS (coalesced) and appends 16B records into a
// dst-bucket-grouped mailbox (hot-window appends, L2-combined); k_phaseB
// streams the mailbox contiguously and LDS-accumulates. Zero random reads.

#define SHIFT 9
#define BSZ 512              // nodes per bucket (1<<SHIFT)
#define EB 2048              // edge-chunk blocks for hist/part
#define SRCMASK 0x7FFFFu     // 19 bits: N <= 524288

static inline int idiv_up(long a, long b) { return (int)((a + b - 1) / b); }

// ---------------- generic hist/scan/partition machinery ----------------
// hist by key-bucket: C[bk*EB + block] = #keys in this block's chunk in bucket bk
__global__ void k_hist(const int* __restrict__ key, long E, long chunk,
                       unsigned* __restrict__ C, int NBUCK) {
    __shared__ unsigned cnt[1024];
    for (int t = threadIdx.x; t < 1024; t += 256) cnt[t] = 0u;
    __syncthreads();
    long e0 = (long)blockIdx.x * chunk;
    long e1 = e0 + chunk; if (e1 > E) e1 = E;
    for (long k = e0 + threadIdx.x; k < e1; k += 256)
        atomicAdd(&cnt[(unsigned)key[k] >> SHIFT], 1u);
    __syncthreads();
    for (int bk = threadIdx.x; bk < NBUCK; bk += 256)
        C[(size_t)bk * EB + blockIdx.x] = cnt[bk];
}

__global__ void k_bsum(const unsigned* __restrict__ in, long L, unsigned* __restrict__ bsum) {
    __shared__ unsigned s[256];
    long base = (long)blockIdx.x * 1024 + threadIdx.x * 4;
    unsigned t = 0;
#pragma unroll
    for (int j = 0; j < 4; ++j) { long idx = base + j; if (idx < L) t += in[idx]; }
    s[threadIdx.x] = t;
    __syncthreads();
    for (int o = 128; o > 0; o >>= 1) {
        if (threadIdx.x < (unsigned)o) s[threadIdx.x] += s[threadIdx.x + o];
        __syncthreads();
    }
    if (threadIdx.x == 0) bsum[blockIdx.x] = s[0];
}

__global__ void k_scan_boff(unsigned* bsum, int NB) {
    __shared__ unsigned s[512];
    unsigned carry = 0;
    for (int base = 0; base < NB; base += 512) {
        int idx = base + threadIdx.x;
        unsigned v = (idx < NB) ? bsum[idx] : 0u;
        s[threadIdx.x] = v;
        __syncthreads();
        for (int o = 1; o < 512; o <<= 1) {
            unsigned a = (threadIdx.x >= (unsigned)o) ? s[threadIdx.x - o] : 0u;
            __syncthreads();
            s[threadIdx.x] += a;
            __syncthreads();
        }
        if (idx < NB) bsum[idx] = carry + s[threadIdx.x] - v;  // exclusive
        unsigned tot = s[511];
        __syncthreads();
        carry += tot;
    }
}

__global__ void k_scan_final(const unsigned* __restrict__ in, long L,
                             const unsigned* __restrict__ boff, unsigned* __restrict__ out) {
    __shared__ unsigned s[256];
    long base = (long)blockIdx.x * 1024 + threadIdx.x * 4;
    unsigned v[4]; unsigned t = 0;
#pragma unroll
    for (int j = 0; j < 4; ++j) { long idx = base + j; v[j] = (idx < L) ? in[idx] : 0u; t += v[j]; }
    s[threadIdx.x] = t;
    __syncthreads();
    for (int o = 1; o < 256; o <<= 1) {
        unsigned a = (threadIdx.x >= (unsigned)o) ? s[threadIdx.x - o] : 0u;
        __syncthreads();
        s[threadIdx.x] += a;
        __syncthreads();
    }
    unsigned run = s[threadIdx.x] - t + boff[blockIdx.x];
#pragma unroll
    for (int j = 0; j < 4; ++j) {
        long idx = base + j;
        if (idx < L) { out[idx] = run; run += v[j]; }
    }
}

// src-sort partition: ES entry = dst<<9 | (src&511), grouped by src-bucket
__global__ void k_part1(const int* __restrict__ src, const int* __restrict__ dst, long E,
                        long chunk, const unsigned* __restrict__ C1off,
                        unsigned* __restrict__ ES, int NBUCK) {
    __shared__ unsigned cur[1024];
    for (int bk = threadIdx.x; bk < NBUCK; bk += 256)
        cur[bk] = C1off[(size_t)bk * EB + blockIdx.x];
    __syncthreads();
    long e0 = (long)blockIdx.x * chunk;
    long e1 = e0 + chunk; if (e1 > E) e1 = E;
    for (long k = e0 + threadIdx.x; k < e1; k += 256) {
        unsigned s = (unsigned)src[k], d = (unsigned)dst[k];
        unsigned bk = s >> SHIFT;
        unsigned pos = atomicAdd(&cur[bk], 1u);  // LDS atomic
        ES[pos] = (d << 9) | (s & (BSZ - 1u));
    }
}

// C2[db*NBUCK + sb] = #edges src-bucket sb -> dst-bucket db
__global__ void k_c2(const unsigned* __restrict__ ES, const unsigned* __restrict__ C1off,
                     long E, int NBUCK, unsigned* __restrict__ C2) {
    __shared__ unsigned cnt[1024];
    for (int t = threadIdx.x; t < 1024; t += 256) cnt[t] = 0u;
    int sb = blockIdx.x;
    long bs = C1off[(size_t)sb * EB];
    long be = (sb + 1 < NBUCK) ? (long)C1off[(size_t)(sb + 1) * EB] : E;
    __syncthreads();
    for (long k = bs + threadIdx.x; k < be; k += 256)
        atomicAdd(&cnt[ES[k] >> 18], 1u);  // db = dst>>9 = entry>>18
    __syncthreads();
    for (int db = threadIdx.x; db < NBUCK; db += 256)
        C2[(size_t)db * NBUCK + sb] = cnt[db];
}

// assign each edge a deterministic mailbox slot; record POS[k] and DL[pos]
__global__ __launch_bounds__(512) void k_pos(const unsigned* __restrict__ ES,
                                             const unsigned* __restrict__ C1off,
                                             const unsigned* __restrict__ C2off, long E,
                                             int NBUCK, unsigned* __restrict__ POS,
                                             unsigned* __restrict__ DL) {
    __shared__ unsigned cur[1024];
    int sb = blockIdx.x;
    for (int db = threadIdx.x; db < NBUCK; db += 512)
        cur[db] = C2off[(size_t)db * NBUCK + sb];
    long bs = C1off[(size_t)sb * EB];
    long be = (sb + 1 < NBUCK) ? (long)C1off[(size_t)(sb + 1) * EB] : E;
    __syncthreads();
    for (long k = bs + threadIdx.x; k < be; k += 512) {
        unsigned e = ES[k];
        unsigned dst = e >> 9;
        unsigned db = dst >> SHIFT;
        unsigned pos = atomicAdd(&cur[db], 1u);  // LDS atomic
        POS[k] = pos;                            // coalesced
        DL[pos] = dst & (BSZ - 1u);              // hot-window append (4B)
    }
}

// dinv from DL (per dst-bucket histogram, streaming reads)
__global__ void k_bdeg2(const unsigned* __restrict__ DL, const unsigned* __restrict__ C2off,
                        long E, int NBUCK, float* __restrict__ dinv, int N) {
    __shared__ unsigned cnt[BSZ];
    for (int t = threadIdx.x; t < BSZ; t += 256) cnt[t] = 0u;
    int db = blockIdx.x;
    long bs = C2off[(size_t)db * NBUCK];
    long be = (db + 1 < NBUCK) ? (long)C2off[(size_t)(db + 1) * NBUCK] : E;
    __syncthreads();
    for (long k = bs + threadIdx.x; k < be; k += 256)
        atomicAdd(&cnt[DL[k]], 1u);
    __syncthreads();
    int base = db << SHIFT;
    for (int t = threadIdx.x; t < BSZ; t += 256) {
        int node = base + t;
        if (node < N) dinv[node] = rsqrtf((float)(cnt[t] + 1u));  // +1 self-loop
    }
}

// expand: per src-bucket, stage 8 channels of y in LDS, append 16B records to MB
template <int ROWW, int HOFF>
__global__ __launch_bounds__(512) void k_expand(const unsigned* __restrict__ ES,
                                                const unsigned* __restrict__ POS,
                                                const unsigned* __restrict__ C1off, long E,
                                                int NBUCK, const __half* __restrict__ y,
                                                __half* __restrict__ MB, int N) {
    __shared__ __half ywin[BSZ * 8];  // 8 KB
    int sb = blockIdx.x;
    int base = sb << SHIFT;
    for (int t = threadIdx.x; t < BSZ; t += 512) {
        int node = base + t;
        uint4 v = make_uint4(0u, 0u, 0u, 0u);
        if (node < N) v = *(const uint4*)(y + (size_t)node * ROWW + HOFF);
        *(uint4*)(ywin + t * 8) = v;
    }
    long bs = C1off[(size_t)sb * EB];
    long be = (sb + 1 < NBUCK) ? (long)C1off[(size_t)(sb + 1) * EB] : E;
    __syncthreads();
    for (long k = bs + threadIdx.x; k < be; k += 512) {
        unsigned e = ES[k];                      // coalesced
        unsigned srclow = e & (BSZ - 1u);
        unsigned pos = POS[k];                   // coalesced
        *(uint4*)(MB + (size_t)pos * 8) = *(const uint4*)(ywin + srclow * 8);
    }
}

// compress: per dst-bucket, stream mailbox range, LDS-accumulate, + self-loop
template <int ROWW, int HOFF>
__global__ __launch_bounds__(512) void k_phaseB(const __half* __restrict__ MB,
                                                const unsigned* __restrict__ DL,
                                                const unsigned* __restrict__ C2off, long E,
                                                int NBUCK, const __half* __restrict__ y,
                                                float* __restrict__ acc, int N) {
    __shared__ float sacc[8 * BSZ];  // 16 KB
    for (int t = threadIdx.x; t < 8 * BSZ; t += 512) sacc[t] = 0.f;
    int db = blockIdx.x;
    long bs = C2off[(size_t)db * NBUCK];
    long be = (db + 1 < NBUCK) ? (long)C2off[(size_t)(db + 1) * NBUCK] : E;
    __syncthreads();
    for (long k = bs + threadIdx.x; k < be; k += 512) {
        unsigned dl = DL[k];                     // coalesced
        uint4 r = *(const uint4*)(MB + (size_t)k * 8);  // coalesced
        const __half2* hp = (const __half2*)&r;
#pragma unroll
        for (int j = 0; j < 4; ++j) {
            float2 f = __half22float2(hp[j]);
            atomicAdd(&sacc[(2 * j + 0) * BSZ + dl], f.x);  // ds_add_f32
            atomicAdd(&sacc[(2 * j + 1) * BSZ + dl], f.y);
        }
    }
    __syncthreads();
    int t = threadIdx.x;  // BSZ == blockDim
    int node = (db << SHIFT) + t;
    if (node < N) {
        const __half* yn = y + (size_t)node * ROWW + HOFF;
        float* op = acc + (size_t)node * ROWW + HOFF;
#pragma unroll
        for (int q = 0; q < 2; ++q) {
            float4 o;
            o.x = sacc[(4 * q + 0) * BSZ + t] + __half2float(yn[4 * q + 0]);
            o.y = sacc[(4 * q + 1) * BSZ + t] + __half2float(yn[4 * q + 1]);
            o.z = sacc[(4 * q + 2) * BSZ + t] + __half2float(yn[4 * q + 2]);
            o.w = sacc[(4 * q + 3) * BSZ + t] + __half2float(yn[4 * q + 3]);
            *(float4*)(op + 4 * q) = o;
        }
    }
}

// ---------------- node kernels (fp16 y) ----------------
__device__ inline uint4 pack8h(const float* o) {
    union { __half2 h2[4]; uint4 u; } z;
    z.h2[0] = __floats2half2_rn(o[0], o[1]);
    z.h2[1] = __floats2half2_rn(o[2], o[3]);
    z.h2[2] = __floats2half2_rn(o[4], o[5]);
    z.h2[3] = __floats2half2_rn(o[6], o[7]);
    return z.u;
}

__global__ void k_node1(const float* __restrict__ x, const float* __restrict__ W1,
                        const float* __restrict__ dinv, __half* __restrict__ y1h, int N) {
    __shared__ float sW[192];  // W1 [12][16]
    if (threadIdx.x < 192) sW[threadIdx.x] = W1[threadIdx.x];
    __syncthreads();
    int i = blockIdx.x * blockDim.x + threadIdx.x;
    if (i >= N) return;
    const float4* xp = (const float4*)(x + (size_t)i * 12);
    float4 a = xp[0], b = xp[1], c = xp[2];
    float xi[12] = {a.x, a.y, a.z, a.w, b.x, b.y, b.z, b.w, c.x, c.y, c.z, c.w};
    float di = dinv[i];
    float o[16];
#pragma unroll
    for (int cc = 0; cc < 16; ++cc) {
        float s = 0.f;
#pragma unroll
        for (int r = 0; r < 12; ++r) s = fmaf(xi[r], sW[r * 16 + cc], s);
        o[cc] = s * di;
    }
    uint4* yp = (uint4*)(y1h + (size_t)i * 16);
    yp[0] = pack8h(o);
    yp[1] = pack8h(o + 8);
}

__global__ void k_node2(const float* __restrict__ acc1, const float* __restrict__ W2,
                        const float* __restrict__ b1, const float* __restrict__ dinv,
                        __half* __restrict__ y2h, int N) {
    __shared__ float sW[128];  // W2 [16][8]
    __shared__ float sb[16];
    if (threadIdx.x < 128) sW[threadIdx.x] = W2[threadIdx.x];
    if (threadIdx.x < 16) sb[threadIdx.x] = b1[threadIdx.x];
    __syncthreads();
    int i = blockIdx.x * blockDim.x + threadIdx.x;
    if (i >= N) return;
    float di = dinv[i];
    const float4* ap = (const float4*)(acc1 + (size_t)i * 16);
    float h[16];
#pragma unroll
    for (int q = 0; q < 4; ++q) {
        float4 v = ap[q];
        h[4 * q + 0] = fmaxf(fmaf(v.x, di, sb[4 * q + 0]), 0.f);
        h[4 * q + 1] = fmaxf(fmaf(v.y, di, sb[4 * q + 1]), 0.f);
        h[4 * q + 2] = fmaxf(fmaf(v.z, di, sb[4 * q + 2]), 0.f);
        h[4 * q + 3] = fmaxf(fmaf(v.w, di, sb[4 * q + 3]), 0.f);
    }
    float o[8];
#pragma unroll
    for (int k = 0; k < 8; ++k) {
        float s = 0.f;
#pragma unroll
        for (int c = 0; c < 16; ++c) s = fmaf(h[c], sW[c * 8 + k], s);
        o[k] = s * di;
    }
    *(uint4*)(y2h + (size_t)i * 8) = pack8h(o);
}

__global__ void k_node3(const float* __restrict__ acc2, const float* __restrict__ b2,
                        const float* __restrict__ fcw, const float* __restrict__ fcb,
                        const float* __restrict__ dinv, float* __restrict__ out, int N) {
    __shared__ float sb[8], sw[8], sfb[1];
    if (threadIdx.x < 8) {
        sb[threadIdx.x] = b2[threadIdx.x];
        sw[threadIdx.x] = fcw[threadIdx.x];
    }
    if (threadIdx.x == 0) sfb[0] = fcb[0];
    __syncthreads();
    int i = blockIdx.x * blockDim.x + threadIdx.x;
    if (i >= N) return;
    float di = dinv[i];
    const float4* ap = (const float4*)(acc2 + (size_t)i * 8);
    float s = sfb[0];
#pragma unroll
    for (int q = 0; q < 2; ++q) {
        float4 v = ap[q];
        s = fmaf(fmaxf(fmaf(v.x, di, sb[4 * q + 0]), 0.f), sw[4 * q + 0], s);
        s = fmaf(fmaxf(fmaf(v.y, di, sb[4 * q + 1]), 0.f), sw[4 * q + 1], s);
        s = fmaf(fmaxf(fmaf(v.z, di, sb[4 * q + 2]), 0.f), sw[4 * q + 2], s);
        s = fmaf(fmaxf(fmaf(v.w, di, sb[4 * q + 3]), 0.f), sw[4 * q + 3], s);
    }
    out[i] = 1.f / (1.f + expf(-s));
}

// ---------------- fallback 1: R5 (dst-bucket random gather) ----------------
__global__ void k_part(const int* __restrict__ src, const int* __restrict__ dst, long E,
                       long chunk, const unsigned* __restrict__ Coff,
                       unsigned* __restrict__ P, int NBUCK) {
    __shared__ unsigned cur[1024];
    for (int bk = threadIdx.x; bk < NBUCK; bk += 256)
        cur[bk] = Coff[(size_t)bk * EB + blockIdx.x];
    __syncthreads();
    long e0 = (long)blockIdx.x * chunk;
    long e1 = e0 + chunk; if (e1 > E) e1 = E;
    for (long k = e0 + threadIdx.x; k < e1; k += 256) {
        unsigned s = (unsigned)src[k], d = (unsigned)dst[k];
        unsigned bk = d >> SHIFT;
        unsigned pos = atomicAdd(&cur[bk], 1u);
        P[pos] = s | ((d & (BSZ - 1u)) << 19);
    }
}

__global__ void k_bdeg(const unsigned* __restrict__ P, const unsigned* __restrict__ Coff,
                       long E, int NBUCK, float* __restrict__ dinv, int N) {
    __shared__ unsigned cnt[BSZ];
    for (int t = threadIdx.x; t < BSZ; t += 256) cnt[t] = 0u;
    int b = blockIdx.x;
    long bs = Coff[(size_t)b * EB];
    long be = (b + 1 < NBUCK) ? (long)Coff[(size_t)(b + 1) * EB] : E;
    __syncthreads();
    for (long k = bs + threadIdx.x; k < be; k += 256)
        atomicAdd(&cnt[P[k] >> 19], 1u);
    __syncthreads();
    int base = b << SHIFT;
    for (int t = threadIdx.x; t < BSZ; t += 256) {
        int node = base + t;
        if (node < N) dinv[node] = rsqrtf((float)(cnt[t] + 1u));
    }
}

template <int C>
__device__ inline void loadrow(const __half* __restrict__ y, unsigned v, uint4* r) {
    unsigned s = v & SRCMASK;
    const uint4* yp = (const uint4*)(y + (size_t)s * C);
#pragma unroll
    for (int q = 0; q < C / 8; ++q) r[q] = yp[q];
}

template <int C>
__device__ inline void scatrow(float* __restrict__ sacc, unsigned v, const uint4* r) {
    unsigned dl = v >> 19;
#pragma unroll
    for (int q = 0; q < C / 8; ++q) {
        const __half2* hp = (const __half2*)&r[q];
#pragma unroll
        for (int j = 0; j < 4; ++j) {
            float2 f = __half22float2(hp[j]);
            atomicAdd(&sacc[(q * 8 + 2 * j + 0) * BSZ + dl], f.x);
            atomicAdd(&sacc[(q * 8 + 2 * j + 1) * BSZ + dl], f.y);
        }
    }
}

template <int C>
__global__ __launch_bounds__(512) void k_agg(const unsigned* __restrict__ P,
                                             const unsigned* __restrict__ Coff, long E, int NBUCK,
                                             const __half* __restrict__ y,
                                             float* __restrict__ accG, int N) {
    __shared__ float sacc[C * BSZ];
    for (int t = threadIdx.x; t < C * BSZ; t += 512) sacc[t] = 0.f;
    int b = blockIdx.x;
    long bs = Coff[(size_t)b * EB];
    long be = (b + 1 < NBUCK) ? (long)Coff[(size_t)(b + 1) * EB] : E;
    __syncthreads();
    const long T = 512;
    long k = bs + threadIdx.x;
    for (; k + 3 * T < be; k += 4 * T) {
        unsigned v0 = P[k], v1 = P[k + T], v2 = P[k + 2 * T], v3 = P[k + 3 * T];
        uint4 r0[C / 8], r1[C / 8], r2[C / 8], r3[C / 8];
        loadrow<C>(y, v0, r0);
        loadrow<C>(y, v1, r1);
        loadrow<C>(y, v2, r2);
        loadrow<C>(y, v3, r3);
        scatrow<C>(sacc, v0, r0);
        scatrow<C>(sacc, v1, r1);
        scatrow<C>(sacc, v2, r2);
        scatrow<C>(sacc, v3, r3);
    }
    for (; k < be; k += T) {
        unsigned v = P[k];
        uint4 r[C / 8];
        loadrow<C>(y, v, r);
        scatrow<C>(sacc, v, r);
    }
    __syncthreads();
    int t = threadIdx.x;
    int node = (b << SHIFT) + t;
    if (node < N) {
        const __half* yn = y + (size_t)node * C;
        float4* op = (float4*)(accG + (size_t)node * C);
#pragma unroll
        for (int q = 0; q < C / 4; ++q) {
            float4 o;
            o.x = sacc[(4 * q + 0) * BSZ + t] + __half2float(yn[4 * q + 0]);
            o.y = sacc[(4 * q + 1) * BSZ + t] + __half2float(yn[4 * q + 1]);
            o.z = sacc[(4 * q + 2) * BSZ + t] + __half2float(yn[4 * q + 2]);
            o.w = sacc[(4 * q + 3) * BSZ + t] + __half2float(yn[4 * q + 3]);
            op[q] = o;
        }
    }
}

// ---------------- fallback 2: R1 (global f32 atomics) ----------------
__global__ void k_deg(const int* __restrict__ dst, long E, unsigned* __restrict__ deg) {
    long i = (long)blockIdx.x * blockDim.x + threadIdx.x;
    long stride = (long)gridDim.x * blockDim.x;
    for (long e = i; e < E; e += stride)
        atomicAdd(&deg[dst[e]], 1u);
}

__global__ void k_dinv(const unsigned* __restrict__ deg, float* __restrict__ dinv, int N) {
    int i = blockIdx.x * blockDim.x + threadIdx.x;
    if (i < N) dinv[i] = rsqrtf((float)(deg[i] + 1u));
}

__global__ void k_node1f(const float* __restrict__ x, const float* __restrict__ W1,
                         const float* __restrict__ dinv, float* __restrict__ y1,
                         float* __restrict__ acc1, int N) {
    __shared__ float sW[192];
    if (threadIdx.x < 192) sW[threadIdx.x] = W1[threadIdx.x];
    __syncthreads();
    int i = blockIdx.x * blockDim.x + threadIdx.x;
    if (i >= N) return;
    const float4* xp = (const float4*)(x + (size_t)i * 12);
    float4 a = xp[0], b = xp[1], c = xp[2];
    float xi[12] = {a.x, a.y, a.z, a.w, b.x, b.y, b.z, b.w, c.x, c.y, c.z, c.w};
    float di = dinv[i];
    float o[16];
#pragma unroll
    for (int cc = 0; cc < 16; ++cc) {
        float s = 0.f;
#pragma unroll
        for (int r = 0; r < 12; ++r) s = fmaf(xi[r], sW[r * 16 + cc], s);
        o[cc] = s * di;
    }
    float4* yp = (float4*)(y1 + (size_t)i * 16);
    float4* ap = (float4*)(acc1 + (size_t)i * 16);
#pragma unroll
    for (int q = 0; q < 4; ++q) {
        float4 v = make_float4(o[4 * q], o[4 * q + 1], o[4 * q + 2], o[4 * q + 3]);
        yp[q] = v; ap[q] = v;
    }
}

__global__ void k_node2f(const float* __restrict__ acc1, const float* __restrict__ W2,
                         const float* __restrict__ b1, const float* __restrict__ dinv,
                         float* __restrict__ y2, float* __restrict__ acc2, int N) {
    __shared__ float sW[128];
    __shared__ float sb[16];
    if (threadIdx.x < 128) sW[threadIdx.x] = W2[threadIdx.x];
    if (threadIdx.x < 16) sb[threadIdx.x] = b1[threadIdx.x];
    __syncthreads();
    int i = blockIdx.x * blockDim.x + threadIdx.x;
    if (i >= N) return;
    float di = dinv[i];
    const float4* ap = (const float4*)(acc1 + (size_t)i * 16);
    float h[16];
#pragma unroll
    for (int q = 0; q < 4; ++q) {
        float4 v = ap[q];
        h[4 * q + 0] = fmaxf(fmaf(v.x, di, sb[4 * q + 0]), 0.f);
        h[4 * q + 1] = fmaxf(fmaf(v.y, di, sb[4 * q + 1]), 0.f);
        h[4 * q + 2] = fmaxf(fmaf(v.z, di, sb[4 * q + 2]), 0.f);
        h[4 * q + 3] = fmaxf(fmaf(v.w, di, sb[4 * q + 3]), 0.f);
    }
    float o[8];
#pragma unroll
    for (int k = 0; k < 8; ++k) {
        float s = 0.f;
#pragma unroll
        for (int c = 0; c < 16; ++c) s = fmaf(h[c], sW[c * 8 + k], s);
        o[k] = s * di;
    }
    float4* yp = (float4*)(y2 + (size_t)i * 8);
    float4* a2 = (float4*)(acc2 + (size_t)i * 8);
#pragma unroll
    for (int q = 0; q < 2; ++q) {
        float4 v = make_float4(o[4 * q], o[4 * q + 1], o[4 * q + 2], o[4 * q + 3]);
        yp[q] = v; a2[q] = v;
    }
}

template <int C>
__global__ void k_edge(const int* __restrict__ src, const int* __restrict__ dst, long E,
                       const float* __restrict__ y, float* __restrict__ acc) {
    long i = (long)blockIdx.x * blockDim.x + threadIdx.x;
    long stride = (long)gridDim.x * blockDim.x;
    for (long e = i; e < E; e += stride) {
        int s = src[e], d = dst[e];
        const float4* ys = (const float4*)(y + (size_t)s * C);
        float* ad = acc + (size_t)d * C;
#pragma unroll
        for (int q = 0; q < C / 4; ++q) {
            float4 v = ys[q];
            unsafeAtomicAdd(ad + 4 * q + 0, v.x);
            unsafeAtomicAdd(ad + 4 * q + 1, v.y);
            unsafeAtomicAdd(ad + 4 * q + 2, v.z);
            unsafeAtomicAdd(ad + 4 * q + 3, v.w);
        }
    }
}

extern "C" void kernel_launch(void* const* d_in, const int* in_sizes, int n_in,
                              void* d_out, int out_size, void* d_ws, size_t ws_size,
                              hipStream_t stream) {
    const float* x   = (const float*)d_in[0];
    const int*   ei  = (const int*)d_in[1];
    const float* W1  = (const float*)d_in[2];
    const float* b1  = (const float*)d_in[3];
    const float* W2  = (const float*)d_in[4];
    const float* b2  = (const float*)d_in[5];
    const float* fcw = (const float*)d_in[6];
    const float* fcb = (const float*)d_in[7];
    float* out = (float*)d_out;

    const long N = in_sizes[0] / 12;
    const long E = in_sizes[1] / 2;
    const int* src = ei;
    const int* dst = ei + E;

    const int NBUCK = idiv_up(N, BSZ);
    const long L1 = (long)NBUCK * EB;            // hist matrix entries
    const int NB1 = idiv_up(L1, 1024);
    const long L2 = (long)NBUCK * NBUCK;         // sb x db matrix
    const int NB2 = idiv_up(L2, 1024);
    const long chunk = (E + EB - 1) / EB;

    const int B = 256;
    const int NG = idiv_up(N, B);

    // ---- main-path workspace layout (~286 MB) ----
    char* ws = (char*)d_ws;
    size_t off = 0;
    auto alloc = [&](size_t bytes) {
        void* p = ws + off;
        off += (bytes + 255) & ~(size_t)255;
        return p;
    };
    unsigned* C1    = (unsigned*)alloc((size_t)L1 * 4);   // scanned in place
    unsigned* bsum1 = (unsigned*)alloc((size_t)NB1 * 4);
    unsigned* ES    = (unsigned*)alloc((size_t)E * 4);    // dst<<9 | srclow
    unsigned* C2    = (unsigned*)alloc((size_t)L2 * 4);   // scanned in place
    unsigned* bsum2 = (unsigned*)alloc((size_t)NB2 * 4);
    unsigned* POS   = (unsigned*)alloc((size_t)E * 4);    // edge -> mailbox slot
    unsigned* DL    = (unsigned*)alloc((size_t)E * 4);    // slot -> dst-low
    __half*   MB    = (__half*)alloc((size_t)E * 8 * 2);  // 16B records, 128 MB
    float*    dinv  = (float*)alloc((size_t)N * 4);
    __half*   y1h   = (__half*)alloc((size_t)N * 16 * 2);
    float*    acc1  = (float*)alloc((size_t)N * 16 * 4);
    __half*   y2h   = y1h;            // y1h dead after B1b (node2 reads acc1 only)
    float*    acc2  = (float*)ES;     // ES dead after last expand
    const bool use_main = (N <= 524288) && (off <= ws_size);

    if (use_main) {
        // src-sort
        k_hist<<<EB, B, 0, stream>>>(src, E, chunk, C1, NBUCK);
        k_bsum<<<NB1, B, 0, stream>>>(C1, L1, bsum1);
        k_scan_boff<<<1, 512, 0, stream>>>(bsum1, NB1);
        k_scan_final<<<NB1, B, 0, stream>>>(C1, L1, bsum1, C1);
        k_part1<<<EB, B, 0, stream>>>(src, dst, E, chunk, C1, ES, NBUCK);
        // sb x db matrix + scan -> mailbox windows
        k_c2<<<NBUCK, B, 0, stream>>>(ES, C1, E, NBUCK, C2);
        k_bsum<<<NB2, B, 0, stream>>>(C2, L2, bsum2);
        k_scan_boff<<<1, 512, 0, stream>>>(bsum2, NB2);
        k_scan_final<<<NB2, B, 0, stream>>>(C2, L2, bsum2, C2);
        // deterministic slot assignment + dst labels + degrees
        k_pos<<<NBUCK, 512, 0, stream>>>(ES, C1, C2, E, NBUCK, POS, DL);
        k_bdeg2<<<NBUCK, B, 0, stream>>>(DL, C2, E, NBUCK, dinv, (int)N);
        // layer 1 (two 8-channel passes)
        k_node1<<<NG, B, 0, stream>>>(x, W1, dinv, y1h, (int)N);
        k_expand<16, 0><<<NBUCK, 512, 0, stream>>>(ES, POS, C1, E, NBUCK, y1h, MB, (int)N);
        k_phaseB<16, 0><<<NBUCK, 512, 0, stream>>>(MB, DL, C2, E, NBUCK, y1h, acc1, (int)N);
        k_expand<16, 8><<<NBUCK, 512, 0, stream>>>(ES, POS, C1, E, NBUCK, y1h, MB, (int)N);
        k_phaseB<16, 8><<<NBUCK, 512, 0, stream>>>(MB, DL, C2, E, NBUCK, y1h, acc1, (int)N);
        // layer 2 (one pass)
        k_node2<<<NG, B, 0, stream>>>(acc1, W2, b1, dinv, y2h, (int)N);
        k_expand<8, 0><<<NBUCK, 512, 0, stream>>>(ES, POS, C1, E, NBUCK, y2h, MB, (int)N);
        k_phaseB<8, 0><<<NBUCK, 512, 0, stream>>>(MB, DL, C2, E, NBUCK, y2h, acc2, (int)N);
        k_node3<<<NG, B, 0, stream>>>(acc2, b2, fcw, fcb, dinv, out, (int)N);
        return;
    }

    // ---- fallback 1: R5 layout (~122 MB) ----
    {
        size_t off5 = 0;
        auto alloc5 = [&](size_t bytes) {
            void* p = ws + off5;
            off5 += (bytes + 255) & ~(size_t)255;
            return p;
        };
        unsigned* C5    = (unsigned*)alloc5((size_t)L1 * 4);
        unsigned* bsum5 = (unsigned*)alloc5((size_t)NB1 * 4);
        unsigned* P5    = (unsigned*)alloc5((size_t)E * 4);
        float*    dinv5 = (float*)alloc5((size_t)N * 4);
        __half*   y1h5  = (__half*)alloc5((size_t)N * 16 * 2);
        float*    acc15 = (float*)alloc5((size_t)N * 16 * 4);
        __half*   y2h5  = y1h5;
        float*    acc25 = acc15;
        if ((N <= 524288) && (off5 <= ws_size)) {
            k_hist<<<EB, B, 0, stream>>>(dst, E, chunk, C5, NBUCK);
            k_bsum<<<NB1, B, 0, stream>>>(C5, L1, bsum5);
            k_scan_boff<<<1, 512, 0, stream>>>(bsum5, NB1);
            k_scan_final<<<NB1, B, 0, stream>>>(C5, L1, bsum5, C5);
            k_part<<<EB, B, 0, stream>>>(src, dst, E, chunk, C5, P5, NBUCK);
            k_bdeg<<<NBUCK, B, 0, stream>>>(P5, C5, E, NBUCK, dinv5, (int)N);
            k_node1<<<NG, B, 0, stream>>>(x, W1, dinv5, y1h5, (int)N);
            k_agg<16><<<NBUCK, 512, 0, stream>>>(P5, C5, E, NBUCK, y1h5, acc15, (int)N);
            k_node2<<<NG, B, 0, stream>>>(acc15, W2, b1, dinv5, y2h5, (int)N);
            k_agg<8><<<NBUCK, 512, 0, stream>>>(P5, C5, E, NBUCK, y2h5, acc25, (int)N);
            k_node3<<<NG, B, 0, stream>>>(acc25, b2, fcw, fcb, dinv5, out, (int)N);
            return;
        }
    }

    // ---- fallback 2: R1 layout (~68 MB) ----
    {
        size_t off2 = 0;
        auto alloc2 = [&](size_t bytes) {
            void* p = ws + off2;
            off2 += (bytes + 255) & ~(size_t)255;
            return p;
        };
        unsigned* degF  = (unsigned*)alloc2((size_t)N * 4);
        float*    dinvF = (float*)alloc2((size_t)N * 4);
        float*    y1F   = (float*)alloc2((size_t)N * 16 * 4);
        float*    acc1F = (float*)alloc2((size_t)N * 16 * 4);
        float*    y2F   = y1F;
        float*    acc2F = y1F + N * 8;
        const int EG = 2048;
        hipMemsetAsync(degF, 0, (size_t)N * 4, stream);
        k_deg<<<EG, B, 0, stream>>>(dst, E, degF);
        k_dinv<<<NG, B, 0, stream>>>(degF, dinvF, (int)N);
        k_node1f<<<NG, B, 0, stream>>>(x, W1, dinvF, y1F, acc1F, (int)N);
        k_edge<16><<<EG, B, 0, stream>>>(src, dst, E, y1F, acc1F);
        k_node2f<<<NG, B, 0, stream>>>(acc1F, W2, b1, dinvF, y2F, acc2F, (int)N);
        k_edge<8><<<EG, B, 0, stream>>>(src, dst, E, y2F, acc2F);
        k_node3<<<NG, B, 0, stream>>>(acc2F, b2, fcw, fcb, dinvF, out, (int)N);
    }
}

// Round 7
// 726.376 us; speedup vs baseline: 1.9563x; 1.9201x over previous
//
#include <hip/hip_runtime.h>
#include <hip/hip_fp16.h>
#include <math.h>

// GCN: h1 = relu(norm_agg(x@W1) + b1); h2 = relu(norm_agg(h1@W2) + b2);
// out = sigmoid(h2@fc_w + fc_b)
// norm_agg(z)[d] = dinv[d]*( sum_{s->d} dinv[s]*z[s] + dinv[d]*z[d] )
//
// Round 7: ws_size in [122MB, 286MB) -> everything must fit ~116MB.
// Cost model: per-edge cost = max(divergent VMEM insts, LDS-atomic chain).
// Fix both: (a) sort bucket edges by dst-low -> same-dst runs accumulate in
// VGPRs, LDS atomics only at run boundaries (~7x fewer); (b) y1 in fp8 e4m3
// (16ch = 16B = ONE divergent load/edge; layer2 fp16 already 16B).

#define SHIFT 9
#define BSZ 512              // nodes per bucket
#define EB 512               // edge-chunk blocks for hist/part
#define SRCMASK 0x7FFFFu     // 19 bits: N <= 524288

typedef float floatx2 __attribute__((ext_vector_type(2)));

static inline int idiv_up(long a, long b) { return (int)((a + b - 1) / b); }

// ---------------- hist / scan / partition ----------------
__global__ void k_hist(const int* __restrict__ key, long E, long chunk,
                       unsigned* __restrict__ C, int NBUCK) {
    __shared__ unsigned cnt[1024];
    for (int t = threadIdx.x; t < 1024; t += 256) cnt[t] = 0u;
    __syncthreads();
    long e0 = (long)blockIdx.x * chunk;
    long e1 = e0 + chunk; if (e1 > E) e1 = E;
    for (long k = e0 + threadIdx.x; k < e1; k += 256)
        atomicAdd(&cnt[(unsigned)key[k] >> SHIFT], 1u);
    __syncthreads();
    for (int bk = threadIdx.x; bk < NBUCK; bk += 256)
        C[(size_t)bk * EB + blockIdx.x] = cnt[bk];
}

__global__ void k_bsum(const unsigned* __restrict__ in, long L, unsigned* __restrict__ bsum) {
    __shared__ unsigned s[256];
    long base = (long)blockIdx.x * 1024 + threadIdx.x * 4;
    unsigned t = 0;
#pragma unroll
    for (int j = 0; j < 4; ++j) { long idx = base + j; if (idx < L) t += in[idx]; }
    s[threadIdx.x] = t;
    __syncthreads();
    for (int o = 128; o > 0; o >>= 1) {
        if (threadIdx.x < (unsigned)o) s[threadIdx.x] += s[threadIdx.x + o];
        __syncthreads();
    }
    if (threadIdx.x == 0) bsum[blockIdx.x] = s[0];
}

__global__ void k_scan_boff(unsigned* bsum, int NB) {
    __shared__ unsigned s[512];
    unsigned carry = 0;
    for (int base = 0; base < NB; base += 512) {
        int idx = base + threadIdx.x;
        unsigned v = (idx < NB) ? bsum[idx] : 0u;
        s[threadIdx.x] = v;
        __syncthreads();
        for (int o = 1; o < 512; o <<= 1) {
            unsigned a = (threadIdx.x >= (unsigned)o) ? s[threadIdx.x - o] : 0u;
            __syncthreads();
            s[threadIdx.x] += a;
            __syncthreads();
        }
        if (idx < NB) bsum[idx] = carry + s[threadIdx.x] - v;  // exclusive
        unsigned tot = s[511];
        __syncthreads();
        carry += tot;
    }
}

__global__ void k_scan_final(const unsigned* __restrict__ in, long L,
                             const unsigned* __restrict__ boff, unsigned* __restrict__ out) {
    __shared__ unsigned s[256];
    long base = (long)blockIdx.x * 1024 + threadIdx.x * 4;
    unsigned v[4]; unsigned t = 0;
#pragma unroll
    for (int j = 0; j < 4; ++j) { long idx = base + j; v[j] = (idx < L) ? in[idx] : 0u; t += v[j]; }
    s[threadIdx.x] = t;
    __syncthreads();
    for (int o = 1; o < 256; o <<= 1) {
        unsigned a = (threadIdx.x >= (unsigned)o) ? s[threadIdx.x - o] : 0u;
        __syncthreads();
        s[threadIdx.x] += a;
        __syncthreads();
    }
    unsigned run = s[threadIdx.x] - t + boff[blockIdx.x];
#pragma unroll
    for (int j = 0; j < 4; ++j) {
        long idx = base + j;
        if (idx < L) { out[idx] = run; run += v[j]; }
    }
}

// dst-bucket partition: P entry = src | dlow<<19
__global__ void k_part(const int* __restrict__ src, const int* __restrict__ dst, long E,
                       long chunk, const unsigned* __restrict__ Coff,
                       unsigned* __restrict__ P, int NBUCK) {
    __shared__ unsigned cur[1024];
    for (int bk = threadIdx.x; bk < NBUCK; bk += 256)
        cur[bk] = Coff[(size_t)bk * EB + blockIdx.x];
    __syncthreads();
    long e0 = (long)blockIdx.x * chunk;
    long e1 = e0 + chunk; if (e1 > E) e1 = E;
    for (long k = e0 + threadIdx.x; k < e1; k += 256) {
        unsigned s = (unsigned)src[k], d = (unsigned)dst[k];
        unsigned bk = d >> SHIFT;
        unsigned pos = atomicAdd(&cur[bk], 1u);  // LDS atomic
        P[pos] = s | ((d & (BSZ - 1u)) << 19);
    }
}

// per-bucket counting sort by dlow; degrees (=dinv) fall out of the histogram
__global__ __launch_bounds__(512) void k_sortdl(const unsigned* __restrict__ P,
                                                const unsigned* __restrict__ Coff, long E,
                                                int NBUCK, unsigned* __restrict__ P2,
                                                float* __restrict__ dinv, int N) {
    __shared__ unsigned cnt[BSZ];
    __shared__ unsigned cur[BSZ];
    int b = blockIdx.x;
    long bs = Coff[(size_t)b * EB];
    long be = (b + 1 < NBUCK) ? (long)Coff[(size_t)(b + 1) * EB] : E;
    cnt[threadIdx.x] = 0u;
    __syncthreads();
    for (long k = bs + threadIdx.x; k < be; k += 512)
        atomicAdd(&cnt[(P[k] >> 19) & 511u], 1u);
    __syncthreads();
    unsigned my = cnt[threadIdx.x];
    int node = (b << SHIFT) + (int)threadIdx.x;
    if (node < N) dinv[node] = rsqrtf((float)(my + 1u));  // +1 self-loop
    // inclusive Hillis-Steele scan of cnt
    for (int o = 1; o < 512; o <<= 1) {
        unsigned a = (threadIdx.x >= (unsigned)o) ? cnt[threadIdx.x - o] : 0u;
        __syncthreads();
        cnt[threadIdx.x] += a;
        __syncthreads();
    }
    cur[threadIdx.x] = cnt[threadIdx.x] - my;  // exclusive -> cursors
    __syncthreads();
    for (long k = bs + threadIdx.x; k < be; k += 512) {
        unsigned v = P[k];
        unsigned pos = atomicAdd(&cur[(v >> 19) & 511u], 1u);
        P2[bs + pos] = v;
    }
}

// ---------------- fp8 helpers ----------------
__device__ inline void dec4_fp8(unsigned w, float* f) {
    floatx2 a = __builtin_amdgcn_cvt_pk_f32_fp8(w, false);
    floatx2 b = __builtin_amdgcn_cvt_pk_f32_fp8(w, true);
    f[0] = a.x; f[1] = a.y; f[2] = b.x; f[3] = b.y;
}

template <int C, bool FP8>
__device__ inline void ld_row(const void* __restrict__ yv, unsigned s, float* f) {
    if (FP8) {  // C==16, 16B fp8 row
        uint4 r = ((const uint4*)yv)[s];
        dec4_fp8(r.x, f + 0); dec4_fp8(r.y, f + 4);
        dec4_fp8(r.z, f + 8); dec4_fp8(r.w, f + 12);
    } else {    // C==8, 16B fp16 row
        uint4 r = *(const uint4*)((const __half*)yv + (size_t)s * 8);
        const __half2* hp = (const __half2*)&r;
#pragma unroll
        for (int j = 0; j < 4; ++j) {
            float2 g = __half22float2(hp[j]);
            f[2 * j] = g.x; f[2 * j + 1] = g.y;
        }
    }
}

// ---------------- aggregation: dl-sorted runs, VGPR accumulate ----------------
template <int C, bool FP8>
__global__ __launch_bounds__(512) void k_aggR(const unsigned* __restrict__ P2,
                                              const unsigned* __restrict__ Coff, long E,
                                              int NBUCK, const void* __restrict__ yv,
                                              float* __restrict__ acc, int N) {
    __shared__ float sacc[C * BSZ];
    for (int t = threadIdx.x; t < C * BSZ; t += 512) sacc[t] = 0.f;
    int b = blockIdx.x;
    long bs = Coff[(size_t)b * EB];
    long be = (b + 1 < NBUCK) ? (long)Coff[(size_t)(b + 1) * EB] : E;
    __syncthreads();
    long len = be - bs;
    long chunk = (len + 511) >> 9;
    long k0 = bs + (long)threadIdx.x * chunk;
    long k1 = k0 + chunk; if (k1 > be) k1 = be;
    float racc[C];
    int cur = -1;
    for (long k = k0; k < k1; ++k) {
        unsigned v = P2[k];                       // thread-sequential, L1-amortized
        int dl = (int)((v >> 19) & 511u);
        unsigned s = v & SRCMASK;
        float row[C];
        ld_row<C, FP8>(yv, s, row);               // ONE divergent 16B load
        if (dl != cur) {
            if (cur >= 0) {
#pragma unroll
                for (int c = 0; c < C; ++c) atomicAdd(&sacc[c * BSZ + cur], racc[c]);
            }
            cur = dl;
#pragma unroll
            for (int c = 0; c < C; ++c) racc[c] = row[c];
        } else {
#pragma unroll
            for (int c = 0; c < C; ++c) racc[c] += row[c];
        }
    }
    if (cur >= 0) {
#pragma unroll
        for (int c = 0; c < C; ++c) atomicAdd(&sacc[c * BSZ + cur], racc[c]);
    }
    __syncthreads();
    int t = threadIdx.x;
    int node = (b << SHIFT) + t;
    if (node < N) {
        float self[C];
        ld_row<C, FP8>(yv, (unsigned)node, self);  // self-loop term
        float* op = acc + (size_t)node * C;
#pragma unroll
        for (int q = 0; q < C / 4; ++q) {
            float4 o;
            o.x = sacc[(4 * q + 0) * BSZ + t] + self[4 * q + 0];
            o.y = sacc[(4 * q + 1) * BSZ + t] + self[4 * q + 1];
            o.z = sacc[(4 * q + 2) * BSZ + t] + self[4 * q + 2];
            o.w = sacc[(4 * q + 3) * BSZ + t] + self[4 * q + 3];
            *(float4*)(op + 4 * q) = o;
        }
    }
}

// ---------------- node kernels ----------------
// y1q[i] = fp8( (x[i]@W1)*dinv[i] )   (16 x e4m3 = one uint4 row)
__global__ void k_node1(const float* __restrict__ x, const float* __restrict__ W1,
                        const float* __restrict__ dinv, uint4* __restrict__ y1q, int N) {
    __shared__ float sW[192];  // W1 [12][16]
    if (threadIdx.x < 192) sW[threadIdx.x] = W1[threadIdx.x];
    __syncthreads();
    int i = blockIdx.x * blockDim.x + threadIdx.x;
    if (i >= N) return;
    const float4* xp = (const float4*)(x + (size_t)i * 12);
    float4 a = xp[0], b = xp[1], c = xp[2];
    float xi[12] = {a.x, a.y, a.z, a.w, b.x, b.y, b.z, b.w, c.x, c.y, c.z, c.w};
    float di = dinv[i];
    float o[16];
#pragma unroll
    for (int cc = 0; cc < 16; ++cc) {
        float s = 0.f;
#pragma unroll
        for (int r = 0; r < 12; ++r) s = fmaf(xi[r], sW[r * 16 + cc], s);
        o[cc] = s * di;
    }
    unsigned w[4];
#pragma unroll
    for (int q = 0; q < 4; ++q) {
        unsigned t = (unsigned)__builtin_amdgcn_cvt_pk_fp8_f32(o[4 * q + 0], o[4 * q + 1], 0, false);
        t = (unsigned)__builtin_amdgcn_cvt_pk_fp8_f32(o[4 * q + 2], o[4 * q + 3], (int)t, true);
        w[q] = t;
    }
    y1q[i] = make_uint4(w[0], w[1], w[2], w[3]);
}

// h1 = relu(acc1*dinv + b1); y2h = fp16( (h1@W2)*dinv )
__global__ void k_node2(const float* __restrict__ acc1, const float* __restrict__ W2,
                        const float* __restrict__ b1, const float* __restrict__ dinv,
                        __half* __restrict__ y2h, int N) {
    __shared__ float sW[128];  // W2 [16][8]
    __shared__ float sb[16];
    if (threadIdx.x < 128) sW[threadIdx.x] = W2[threadIdx.x];
    if (threadIdx.x < 16) sb[threadIdx.x] = b1[threadIdx.x];
    __syncthreads();
    int i = blockIdx.x * blockDim.x + threadIdx.x;
    if (i >= N) return;
    float di = dinv[i];
    const float4* ap = (const float4*)(acc1 + (size_t)i * 16);
    float h[16];
#pragma unroll
    for (int q = 0; q < 4; ++q) {
        float4 v = ap[q];
        h[4 * q + 0] = fmaxf(fmaf(v.x, di, sb[4 * q + 0]), 0.f);
        h[4 * q + 1] = fmaxf(fmaf(v.y, di, sb[4 * q + 1]), 0.f);
        h[4 * q + 2] = fmaxf(fmaf(v.z, di, sb[4 * q + 2]), 0.f);
        h[4 * q + 3] = fmaxf(fmaf(v.w, di, sb[4 * q + 3]), 0.f);
    }
    float o[8];
#pragma unroll
    for (int k = 0; k < 8; ++k) {
        float s = 0.f;
#pragma unroll
        for (int c = 0; c < 16; ++c) s = fmaf(h[c], sW[c * 8 + k], s);
        o[k] = s * di;
    }
    union { __half2 h2[4]; uint4 u; } z;
    z.h2[0] = __floats2half2_rn(o[0], o[1]);
    z.h2[1] = __floats2half2_rn(o[2], o[3]);
    z.h2[2] = __floats2half2_rn(o[4], o[5]);
    z.h2[3] = __floats2half2_rn(o[6], o[7]);
    *(uint4*)(y2h + (size_t)i * 8) = z.u;
}

// h2 = relu(acc2*dinv + b2); out = sigmoid(h2@fc_w + fc_b)
__global__ void k_node3(const float* __restrict__ acc2, const float* __restrict__ b2,
                        const float* __restrict__ fcw, const float* __restrict__ fcb,
                        const float* __restrict__ dinv, float* __restrict__ out, int N) {
    __shared__ float sb[8], sw[8], sfb[1];
    if (threadIdx.x < 8) {
        sb[threadIdx.x] = b2[threadIdx.x];
        sw[threadIdx.x] = fcw[threadIdx.x];
    }
    if (threadIdx.x == 0) sfb[0] = fcb[0];
    __syncthreads();
    int i = blockIdx.x * blockDim.x + threadIdx.x;
    if (i >= N) return;
    float di = dinv[i];
    const float4* ap = (const float4*)(acc2 + (size_t)i * 8);
    float s = sfb[0];
#pragma unroll
    for (int q = 0; q < 2; ++q) {
        float4 v = ap[q];
        s = fmaf(fmaxf(fmaf(v.x, di, sb[4 * q + 0]), 0.f), sw[4 * q + 0], s);
        s = fmaf(fmaxf(fmaf(v.y, di, sb[4 * q + 1]), 0.f), sw[4 * q + 1], s);
        s = fmaf(fmaxf(fmaf(v.z, di, sb[4 * q + 2]), 0.f), sw[4 * q + 2], s);
        s = fmaf(fmaxf(fmaf(v.w, di, sb[4 * q + 3]), 0.f), sw[4 * q + 3], s);
    }
    out[i] = 1.f / (1.f + expf(-s));
}

// ---------------- fallback: R1 (global f32 atomics, 68MB) ----------------
__global__ void k_deg(const int* __restrict__ dst, long E, unsigned* __restrict__ deg) {
    long i = (long)blockIdx.x * blockDim.x + threadIdx.x;
    long stride = (long)gridDim.x * blockDim.x;
    for (long e = i; e < E; e += stride)
        atomicAdd(&deg[dst[e]], 1u);
}

__global__ void k_dinv(const unsigned* __restrict__ deg, float* __restrict__ dinv, int N) {
    int i = blockIdx.x * blockDim.x + threadIdx.x;
    if (i < N) dinv[i] = rsqrtf((float)(deg[i] + 1u));
}

__global__ void k_node1f(const float* __restrict__ x, const float* __restrict__ W1,
                         const float* __restrict__ dinv, float* __restrict__ y1,
                         float* __restrict__ acc1, int N) {
    __shared__ float sW[192];
    if (threadIdx.x < 192) sW[threadIdx.x] = W1[threadIdx.x];
    __syncthreads();
    int i = blockIdx.x * blockDim.x + threadIdx.x;
    if (i >= N) return;
    const float4* xp = (const float4*)(x + (size_t)i * 12);
    float4 a = xp[0], b = xp[1], c = xp[2];
    float xi[12] = {a.x, a.y, a.z, a.w, b.x, b.y, b.z, b.w, c.x, c.y, c.z, c.w};
    float di = dinv[i];
    float o[16];
#pragma unroll
    for (int cc = 0; cc < 16; ++cc) {
        float s = 0.f;
#pragma unroll
        for (int r = 0; r < 12; ++r) s = fmaf(xi[r], sW[r * 16 + cc], s);
        o[cc] = s * di;
    }
    float4* yp = (float4*)(y1 + (size_t)i * 16);
    float4* ap = (float4*)(acc1 + (size_t)i * 16);
#pragma unroll
    for (int q = 0; q < 4; ++q) {
        float4 v = make_float4(o[4 * q], o[4 * q + 1], o[4 * q + 2], o[4 * q + 3]);
        yp[q] = v; ap[q] = v;
    }
}

__global__ void k_node2f(const float* __restrict__ acc1, const float* __restrict__ W2,
                         const float* __restrict__ b1, const float* __restrict__ dinv,
                         float* __restrict__ y2, float* __restrict__ acc2, int N) {
    __shared__ float sW[128];
    __shared__ float sb[16];
    if (threadIdx.x < 128) sW[threadIdx.x] = W2[threadIdx.x];
    if (threadIdx.x < 16) sb[threadIdx.x] = b1[threadIdx.x];
    __syncthreads();
    int i = blockIdx.x * blockDim.x + threadIdx.x;
    if (i >= N) return;
    float di = dinv[i];
    const float4* ap = (const float4*)(acc1 + (size_t)i * 16);
    float h[16];
#pragma unroll
    for (int q = 0; q < 4; ++q) {
        float4 v = ap[q];
        h[4 * q + 0] = fmaxf(fmaf(v.x, di, sb[4 * q + 0]), 0.f);
        h[4 * q + 1] = fmaxf(fmaf(v.y, di, sb[4 * q + 1]), 0.f);
        h[4 * q + 2] = fmaxf(fmaf(v.z, di, sb[4 * q + 2]), 0.f);
        h[4 * q + 3] = fmaxf(fmaf(v.w, di, sb[4 * q + 3]), 0.f);
    }
    float o[8];
#pragma unroll
    for (int k = 0; k < 8; ++k) {
        float s = 0.f;
#pragma unroll
        for (int c = 0; c < 16; ++c) s = fmaf(h[c], sW[c * 8 + k], s);
        o[k] = s * di;
    }
    float4* yp = (float4*)(y2 + (size_t)i * 8);
    float4* a2 = (float4*)(acc2 + (size_t)i * 8);
#pragma unroll
    for (int q = 0; q < 2; ++q) {
        float4 v = make_float4(o[4 * q], o[4 * q + 1], o[4 * q + 2], o[4 * q + 3]);
        yp[q] = v; a2[q] = v;
    }
}

template <int C>
__global__ void k_edge(const int* __restrict__ src, const int* __restrict__ dst, long E,
                       const float* __restrict__ y, float* __restrict__ acc) {
    long i = (long)blockIdx.x * blockDim.x + threadIdx.x;
    long stride = (long)gridDim.x * blockDim.x;
    for (long e = i; e < E; e += stride) {
        int s = src[e], d = dst[e];
        const float4* ys = (const float4*)(y + (size_t)s * C);
        float* ad = acc + (size_t)d * C;
#pragma unroll
        for (int q = 0; q < C / 4; ++q) {
            float4 v = ys[q];
            unsafeAtomicAdd(ad + 4 * q + 0, v.x);
            unsafeAtomicAdd(ad + 4 * q + 1, v.y);
            unsafeAtomicAdd(ad + 4 * q + 2, v.z);
            unsafeAtomicAdd(ad + 4 * q + 3, v.w);
        }
    }
}

extern "C" void kernel_launch(void* const* d_in, const int* in_sizes, int n_in,
                              void* d_out, int out_size, void* d_ws, size_t ws_size,
                              hipStream_t stream) {
    const float* x   = (const float*)d_in[0];
    const int*   ei  = (const int*)d_in[1];
    const float* W1  = (const float*)d_in[2];
    const float* b1  = (const float*)d_in[3];
    const float* W2  = (const float*)d_in[4];
    const float* b2  = (const float*)d_in[5];
    const float* fcw = (const float*)d_in[6];
    const float* fcb = (const float*)d_in[7];
    float* out = (float*)d_out;

    const long N = in_sizes[0] / 12;
    const long E = in_sizes[1] / 2;
    const int* src = ei;
    const int* dst = ei + E;

    const int NBUCK = idiv_up(N, BSZ);
    const long L1 = (long)NBUCK * EB;
    const int NB1 = idiv_up(L1, 1024);
    const long chunk = (E + EB - 1) / EB;

    const int B = 256;
    const int NG = idiv_up(N, B);

    // ---- primary layout (~116 MB) ----
    char* ws = (char*)d_ws;
    size_t off = 0;
    auto alloc = [&](size_t bytes) {
        void* p = ws + off;
        off += (bytes + 255) & ~(size_t)255;
        return p;
    };
    unsigned* C1   = (unsigned*)alloc((size_t)L1 * 4);   // scanned in place -> Coff
    unsigned* bsum = (unsigned*)alloc((size_t)NB1 * 4);
    unsigned* P    = (unsigned*)alloc((size_t)E * 4);    // src | dlow<<19 (dst-bucketed)
    unsigned* P2   = (unsigned*)alloc((size_t)E * 4);    // dl-sorted within bucket
    float*    dinv = (float*)alloc((size_t)N * 4);
    uint4*    y1q  = (uint4*)alloc((size_t)N * 16);      // fp8 rows, 16B/node
    float*    acc1 = (float*)alloc((size_t)N * 16 * 4);
    __half*   y2h  = (__half*)alloc((size_t)N * 8 * 2);
    float*    acc2 = acc1;                               // acc1 dead after node2
    const bool use_main = (N <= 524288) && (off <= ws_size);

    if (use_main) {
        k_hist<<<EB, B, 0, stream>>>(dst, E, chunk, C1, NBUCK);
        k_bsum<<<NB1, B, 0, stream>>>(C1, L1, bsum);
        k_scan_boff<<<1, 512, 0, stream>>>(bsum, NB1);
        k_scan_final<<<NB1, B, 0, stream>>>(C1, L1, bsum, C1);
        k_part<<<EB, B, 0, stream>>>(src, dst, E, chunk, C1, P, NBUCK);
        k_sortdl<<<NBUCK, 512, 0, stream>>>(P, C1, E, NBUCK, P2, dinv, (int)N);
        k_node1<<<NG, B, 0, stream>>>(x, W1, dinv, y1q, (int)N);
        k_aggR<16, true><<<NBUCK, 512, 0, stream>>>(P2, C1, E, NBUCK, y1q, acc1, (int)N);
        k_node2<<<NG, B, 0, stream>>>(acc1, W2, b1, dinv, y2h, (int)N);
        k_aggR<8, false><<<NBUCK, 512, 0, stream>>>(P2, C1, E, NBUCK, y2h, acc2, (int)N);
        k_node3<<<NG, B, 0, stream>>>(acc2, b2, fcw, fcb, dinv, out, (int)N);
        return;
    }

    // ---- fallback: R1 layout (~68 MB) ----
    {
        size_t off2 = 0;
        auto alloc2 = [&](size_t bytes) {
            void* p = ws + off2;
            off2 += (bytes + 255) & ~(size_t)255;
            return p;
        };
        unsigned* degF  = (unsigned*)alloc2((size_t)N * 4);
        float*    dinvF = (float*)alloc2((size_t)N * 4);
        float*    y1F   = (float*)alloc2((size_t)N * 16 * 4);
        float*    acc1F = (float*)alloc2((size_t)N * 16 * 4);
        float*    y2F   = y1F;
        float*    acc2F = y1F + N * 8;
        const int EG = 2048;
        hipMemsetAsync(degF, 0, (size_t)N * 4, stream);
        k_deg<<<EG, B, 0, stream>>>(dst, E, degF);
        k_dinv<<<NG, B, 0, stream>>>(degF, dinvF, (int)N);
        k_node1f<<<NG, B, 0, stream>>>(x, W1, dinvF, y1F, acc1F, (int)N);
        k_edge<16><<<EG, B, 0, stream>>>(src, dst, E, y1F, acc1F);
        k_node2f<<<NG, B, 0, stream>>>(acc1F, W2, b1, dinvF, y2F, acc2F, (int)N);
        k_edge<8><<<EG, B, 0, stream>>>(src, dst, E, y2F, acc2F);
        k_node3<<<NG, B, 0, stream>>>(acc2F, b2, fcw, fcb, dinvF, out, (int)N);
    }
}